// Round 6
// baseline (315.434 us; speedup 1.0000x reference)
//
#include <hip/hip_runtime.h>
#include <stdint.h>

typedef __attribute__((ext_vector_type(8))) short bf16x8;
typedef __attribute__((ext_vector_type(4))) float f32x4;

#define CAP 64   // bucket slots per node: slot 0 = self, 1..63 = neighbors (Poisson lambda=12)
#define BREPS 3  // ATTRIBUTION PROBE: bucket edge-pass runs 3x (rep 0 real, reps 1-2 against a
                 // disjoint dummy region with identical traffic). Revert to 1 after reading.

__device__ __forceinline__ float bf2f(unsigned int u) {
    union { unsigned int i; float f; } v; v.i = u << 16; return v.f;
}
__device__ __forceinline__ unsigned int f2bf(float f) {
    union { float f; unsigned int i; } v; v.f = f;
    unsigned int b = v.i;
    b += 0x7FFFu + ((b >> 16) & 1u);   // round-to-nearest-even
    return b >> 16;
}

// ---------------- bucket build (degree count + scatter) + fused W transpose/convert ----------------
// neighbors land at slot+1 (slot 0 reserved for self, written by gemm128's padding pass)

__global__ void bucket_kernel(const int* __restrict__ src, const int* __restrict__ dst,
                              int* __restrict__ counts, unsigned short* __restrict__ bucket,
                              int* __restrict__ dcounts, unsigned short* __restrict__ dbucket,
                              int E,
                              const float* __restrict__ W1, const float* __restrict__ W2,
                              unsigned short* __restrict__ Wt1, unsigned short* __restrict__ Wt2) {
    int t = blockIdx.x * 256 + threadIdx.x;
    if (t < 32768) {                    // blocks 0..127 also convert weights (x1, real)
        const float* W = (t < 16384) ? W1 : W2;
        unsigned short* O = (t < 16384) ? Wt1 : Wt2;
        int i = t & 16383;              // i = n*128 + k ; Wt[n][k] = bf16(W[k][n])
        O[i] = (unsigned short)f2bf(W[(i & 127) * 128 + (i >> 7)]);
    }
#pragma unroll 1
    for (int rep = 0; rep < BREPS; ++rep) {
        asm volatile("" ::: "memory");   // force re-load of src/dst each rep
        if (t < E) {
            int s = src[t], d = dst[t];
            if (rep == 0) {
                int slot = atomicAdd(&counts[d], 1);
                if (slot < CAP - 1) bucket[(size_t)d * CAP + slot + 1] = (unsigned short)s;
            } else {
                // identical traffic shape against dummy region; garbage-based slot masked so
                // the scatter store always lands (realistic RMW traffic), disjoint from real.
                int slot = atomicAdd(&dcounts[d], 1) & (CAP - 2);
                dbucket[(size_t)d * CAP + slot + 1] = (unsigned short)s;
            }
        }
    }
}

// ---------------- GEMM: G_bf16[M,128] = rsqrt(deg+1)[row] * (A_f32[M,128] @ W) ----------------
// Also: writes self into bucket slot 0, pads tail with sentinel (= M) to ceil16(1+deg),
// and zeroes g row M (sentinel target).

__global__ __launch_bounds__(256) void gemm128(const float* __restrict__ A,
                                               const unsigned short* __restrict__ Wt,
                                               const int* __restrict__ counts,
                                               unsigned short* __restrict__ bucket,
                                               unsigned short* __restrict__ G, int M) {
    int t = threadIdx.x;
    int wave = t >> 6, lane = t & 63;
    int mrow = lane & 15, quad = lane >> 4;

    // bucket self + tail padding: 4 threads per row
    {
        int row = blockIdx.x * 64 + (t >> 2);
        if (row < M) {
            int rows = 1 + min(counts[row], CAP - 1);
            int pe = (rows + 15) & ~15;               // >= 16 always
            if ((t & 3) == 0) bucket[(size_t)row * CAP] = (unsigned short)row;   // self
            for (int idx = rows + (t & 3); idx < pe; idx += 4)
                bucket[(size_t)row * CAP + idx] = (unsigned short)M;             // sentinel -> zero row
        }
    }
    // zero row M of G (the sentinel target)
    if (blockIdx.x == 0 && t < 64)
        ((unsigned int*)G)[(size_t)M * 64 + t] = 0u;

    int m0 = (blockIdx.x * 4 + wave) * 16;
    int arow = m0 + mrow;
    int srow = arow < M ? arow : M - 1;
    const float* Arow = A + (size_t)srow * 128;

    f32x4 acc[8];
#pragma unroll
    for (int nt = 0; nt < 8; ++nt) acc[nt] = (f32x4){0.f, 0.f, 0.f, 0.f};

#pragma unroll
    for (int kb = 0; kb < 4; ++kb) {
        f32x4 lo = *(const f32x4*)(Arow + kb * 32 + quad * 8);
        f32x4 hi = *(const f32x4*)(Arow + kb * 32 + quad * 8 + 4);
        bf16x8 a;
#pragma unroll
        for (int i = 0; i < 4; ++i) { a[i] = (short)f2bf(lo[i]); a[i + 4] = (short)f2bf(hi[i]); }
#pragma unroll
        for (int nt = 0; nt < 8; ++nt) {
            bf16x8 b = *(const bf16x8*)(Wt + (size_t)(nt * 16 + mrow) * 128 + kb * 32 + quad * 8);
            acc[nt] = __builtin_amdgcn_mfma_f32_16x16x32_bf16(a, b, acc[nt], 0, 0, 0);
        }
    }

#pragma unroll
    for (int r = 0; r < 4; ++r) {
        int row = m0 + quad * 4 + r;               // C/D: col=lane&15, row=quad*4+reg
        if (row < M) {
            float dr = rsqrtf((float)counts[row] + 1.0f);
#pragma unroll
            for (int nt = 0; nt < 8; ++nt)
                G[(size_t)row * 128 + nt * 16 + mrow] = (unsigned short)f2bf(acc[nt][r] * dr);
        }
    }
}

// ---------------- aggregation kernel: wide-gather version ----------------
// 16 nodes / block (4 per wave). Row list per node = bucket[n*CAP .. ] = {self, neighbors,
// sentinel pad} in 16-row chunks. Each 256 B row is fetched by 16 lanes x 16 B (dwordx4),
// so ONE load instruction covers 4 rows (lane-group g -> slot 4q+g). Lane (group, p):
// accumulates cols p*8..p*8+7 over its quarter of rows; 2-step shfl_xor butterfly (16, 32)
// merges groups. All 4 nodes' chunk0 (16 loads) issued up front.
// FINAL=false: +bias,relu -> LDS -> 16x128 @ 128x128 MFMA -> dinv scale -> G2 (bf16)
// FINAL=true : +bias,relu -> out (f32)

template <bool FINAL>
__global__ __launch_bounds__(256) void agg_kernel(const unsigned short* __restrict__ g,
                                                  const int* __restrict__ counts,
                                                  const unsigned short* __restrict__ bucket,
                                                  const float* __restrict__ bias,
                                                  const unsigned short* __restrict__ Wt,
                                                  unsigned short* __restrict__ G2,
                                                  float* __restrict__ outf,
                                                  int N) {
    __shared__ __align__(16) unsigned short As[FINAL ? 1 : 16][136];   // +8 pad
    int wave = threadIdx.x >> 6, lane = threadIdx.x & 63;
    int p = lane & 15, grp = lane >> 4;
    const char* gb = (const char*)g;
    int nb0 = blockIdx.x * 16 + wave * 4;

    if (!FINAL && blockIdx.x == 0 && threadIdx.x < 64)
        ((unsigned int*)G2)[(size_t)N * 64 + threadIdx.x] = 0u;        // zero row for next layer

    // bias for this lane's 8 columns (same for all 4 groups)
    float4 bva = ((const float4*)bias)[p * 2];
    float4 bvb = ((const float4*)bias)[p * 2 + 1];

    // metadata
    int degs[4]; unsigned int svs[4];
#pragma unroll
    for (int i = 0; i < 4; ++i) {
        int n = min(nb0 + i, N - 1);
        degs[i] = counts[n];
        svs[i]  = bucket[(size_t)n * CAP + lane];
    }

    // chunk0 for all 4 nodes: 16 wide loads in flight (64 rows)
    uint4 vq[4][4];
#pragma unroll
    for (int i = 0; i < 4; ++i)
#pragma unroll
        for (int q = 0; q < 4; ++q) {
            int s = __shfl((int)svs[i], 4 * q + grp);
            vq[i][q] = *(const uint4*)(gb + (size_t)s * 256 + p * 16);
        }

#pragma unroll
    for (int i = 0; i < 4; ++i) {
        int deg = degs[i];
        int rows = 1 + min(deg, CAP - 1);
        int mr = (rows + 15) & ~15;
        float di = rsqrtf((float)deg + 1.0f);
        float acc[8];
#pragma unroll
        for (int k = 0; k < 8; ++k) acc[k] = 0.f;
#pragma unroll
        for (int q = 0; q < 4; ++q)
#pragma unroll
            for (int d = 0; d < 4; ++d) {
                unsigned int v = (&vq[i][q].x)[d];
                acc[d * 2]     += bf2f(v & 0xFFFFu);
                acc[d * 2 + 1] += bf2f(v >> 16);
            }
        // tail chunks (rows > 16, ~15% of nodes)
#pragma unroll 1
        for (int j0 = 16; j0 < mr; j0 += 16) {
            uint4 tq[4];
#pragma unroll
            for (int q = 0; q < 4; ++q) {
                int s = __shfl((int)svs[i], j0 + 4 * q + grp);
                tq[q] = *(const uint4*)(gb + (size_t)s * 256 + p * 16);
            }
#pragma unroll
            for (int q = 0; q < 4; ++q)
#pragma unroll
                for (int d = 0; d < 4; ++d) {
                    unsigned int v = (&tq[q].x)[d];
                    acc[d * 2]     += bf2f(v & 0xFFFFu);
                    acc[d * 2 + 1] += bf2f(v >> 16);
                }
        }
        // merge the 4 lane-groups (each summed 1/4 of the rows)
#pragma unroll
        for (int k = 0; k < 8; ++k) {
            acc[k] += __shfl_xor(acc[k], 16);
            acc[k] += __shfl_xor(acc[k], 32);
        }
        float o[8];
        o[0] = fmaxf(acc[0] * di + bva.x, 0.f);
        o[1] = fmaxf(acc[1] * di + bva.y, 0.f);
        o[2] = fmaxf(acc[2] * di + bva.z, 0.f);
        o[3] = fmaxf(acc[3] * di + bva.w, 0.f);
        o[4] = fmaxf(acc[4] * di + bvb.x, 0.f);
        o[5] = fmaxf(acc[5] * di + bvb.y, 0.f);
        o[6] = fmaxf(acc[6] * di + bvb.z, 0.f);
        o[7] = fmaxf(acc[7] * di + bvb.w, 0.f);

        if (FINAL) {
            if (grp == i) {                        // disjoint lanes across the i-loop
                int n = nb0 + i;
                if (n < N) {
                    float4* op = (float4*)(outf + (size_t)n * 128 + p * 8);
                    op[0] = make_float4(o[0], o[1], o[2], o[3]);
                    op[1] = make_float4(o[4], o[5], o[6], o[7]);
                }
            }
        } else {
            if (grp == i) {
                uint4 w;
                w.x = f2bf(o[0]) | (f2bf(o[1]) << 16);
                w.y = f2bf(o[2]) | (f2bf(o[3]) << 16);
                w.z = f2bf(o[4]) | (f2bf(o[5]) << 16);
                w.w = f2bf(o[6]) | (f2bf(o[7]) << 16);
                *(uint4*)&As[wave * 4 + i][p * 8] = w;   // row stride 272 B (16B-aligned)
            }
        }
    }

    if (FINAL) return;

    __syncthreads();

    // GEMM phase: 16x128 @ 128x128; wave w covers output cols [w*32, w*32+32)
    int mrow = lane & 15, quad = lane >> 4;
    f32x4 acc2[2];
    acc2[0] = (f32x4){0.f, 0.f, 0.f, 0.f};
    acc2[1] = (f32x4){0.f, 0.f, 0.f, 0.f};
#pragma unroll
    for (int kb = 0; kb < 4; ++kb) {
        bf16x8 a = *(const bf16x8*)(&As[mrow][kb * 32 + quad * 8]);
#pragma unroll
        for (int q = 0; q < 2; ++q) {
            int nt = wave * 2 + q;
            bf16x8 b = *(const bf16x8*)(Wt + (size_t)(nt * 16 + mrow) * 128 + kb * 32 + quad * 8);
            acc2[q] = __builtin_amdgcn_mfma_f32_16x16x32_bf16(a, b, acc2[q], 0, 0, 0);
        }
    }
#pragma unroll
    for (int r = 0; r < 4; ++r) {
        int row = blockIdx.x * 16 + quad * 4 + r;
        if (row < N) {
            float dr = rsqrtf((float)counts[row] + 1.0f);
#pragma unroll
            for (int q = 0; q < 2; ++q) {
                int nt = wave * 2 + q;
                G2[(size_t)row * 128 + nt * 16 + mrow] = (unsigned short)f2bf(acc2[q][r] * dr);
            }
        }
    }
}

// ---------------- launch ----------------

extern "C" void kernel_launch(void* const* d_in, const int* in_sizes, int n_in,
                              void* d_out, int out_size, void* d_ws, size_t ws_size,
                              hipStream_t stream) {
    const float* x  = (const float*)d_in[0];
    const int*   ei = (const int*)d_in[1];
    const float* W1 = (const float*)d_in[2];
    const float* b1 = (const float*)d_in[3];
    const float* W2 = (const float*)d_in[4];
    const float* b2 = (const float*)d_in[5];
    float* out = (float*)d_out;

    int N = in_sizes[0] / 128;
    int E = in_sizes[1] / 2;
    const int* src = ei;
    const int* dst = ei + E;

    char* p = (char*)d_ws;
    auto alloc = [&](size_t bytes) {
        char* r = p; p += (bytes + 255) & ~(size_t)255; return r;
    };
    int*            counts  = (int*)           alloc((size_t)N * 4);
    unsigned short* bucket  = (unsigned short*)alloc((size_t)N * CAP * 2);
    unsigned short* g1      = (unsigned short*)alloc((size_t)(N + 1) * 128 * 2);  // bf16 + zero row
    unsigned short* g2      = (unsigned short*)alloc((size_t)(N + 1) * 128 * 2);  // bf16 + zero row
    unsigned short* Wt1     = (unsigned short*)alloc(16384 * 2);                  // bf16 W1^T
    unsigned short* Wt2     = (unsigned short*)alloc(16384 * 2);                  // bf16 W2^T
    int*            dcounts = (int*)           alloc((size_t)N * 4);              // probe dummy
    unsigned short* dbucket = (unsigned short*)alloc((size_t)N * CAP * 2);        // probe dummy

    hipMemsetAsync(counts, 0, (size_t)N * 4, stream);
    bucket_kernel<<<(E + 255) / 256, 256, 0, stream>>>(src, dst, counts, bucket,
                                                       dcounts, dbucket, E,
                                                       W1, W2, Wt1, Wt2);

    gemm128<<<(N + 63) / 64, 256, 0, stream>>>(x, Wt1, counts, bucket, g1, N);
    agg_kernel<false><<<(N + 15) / 16, 256, 0, stream>>>(g1, counts, bucket, b1, Wt2, g2, nullptr, N);
    agg_kernel<true ><<<(N + 15) / 16, 256, 0, stream>>>(g2, counts, bucket, b2, nullptr, nullptr, out, N);
}